// Round 19
// baseline (51.327 us; speedup 1.0000x reference)
//
#include <hip/hip_runtime.h>

// SSIM loss v18: v17 (packed epilogue, unscaled s'/d', block-of-2 windows) with
// TH=16 (4 rolled blocks) to amortize the 6-pair preamble over 2x the output
// rows (1.25 vs 2.0 rows-loaded/row-output), + symmetric-pair 9-tap hblur
// (w[k]=w[8-k]: 9 ops vs 10 per col-channel). Occupancy is provably not
// binding (v17: -10pp occupancy, +4% perf), so halved wave count is free.

namespace {
constexpr int W = 320, H = 320, B = 128;
constexpr int TH = 16;
constexpr int NSTRIPE = H / TH;     // 20
constexpr int NWAVE = B * NSTRIPE;  // 2560
constexpr float C1 = 1.0e-4f;
constexpr float C2 = 9.0e-4f;
constexpr int NSLOT = 128;
constexpr int SSTR = 16;
}

typedef _Float16 h2 __attribute__((ext_vector_type(2)));
typedef float f4a __attribute__((ext_vector_type(4), aligned(4)));

__device__ __forceinline__ float fdot2f(h2 a, h2 b, float c) {
#if __has_builtin(__builtin_amdgcn_fdot2)
  return __builtin_amdgcn_fdot2(a, b, c, false);
#else
  return fmaf((float)a.x, (float)b.x, fmaf((float)a.y, (float)b.y, c));
#endif
}

__device__ __forceinline__ float rcpf(float x) {
  float r;
  asm("v_rcp_f32 %0, %1" : "=v"(r) : "v"(x));
  return r;
}

__device__ __forceinline__ h2 pack2(float a, float b) {
  return h2{(_Float16)a, (_Float16)b};
}

__device__ __forceinline__ h2 pkrtz(float a, float b) {
#if __has_builtin(__builtin_amdgcn_cvt_pkrtz)
  return __builtin_bit_cast(h2, __builtin_amdgcn_cvt_pkrtz(a, b));
#else
  return pack2(a, b);
#endif
}

// lane i <- lane i-1, lane 0 <- 0 (wave_shr:1, bound_ctrl). [HW-verified]
__device__ __forceinline__ h2 dpp_up1(h2 v) {
  int r = __builtin_amdgcn_update_dpp(0, __builtin_bit_cast(int, v),
                                      0x138, 0xF, 0xF, true);
  return __builtin_bit_cast(h2, r);
}
// lane i <- lane i+1, lane 63 <- 0 (wave_shl:1, bound_ctrl). [HW-verified]
__device__ __forceinline__ h2 dpp_dn1(h2 v) {
  int r = __builtin_amdgcn_update_dpp(0, __builtin_bit_cast(int, v),
                                      0x130, 0xF, 0xF, true);
  return __builtin_bit_cast(h2, r);
}

#define LOADROW_V(PTR, A)                                                     \
  do {                                                                        \
    const f4a q_ = *(const f4a*)(PTR);                                        \
    A[0] = q_.x; A[1] = q_.y; A[2] = q_.z; A[3] = q_.w;                       \
    A[4] = (PTR)[4];                                                          \
  } while (0)

#define LOADP_RAW(ROW, A0, B0, A1, B1)                                        \
  do {                                                                        \
    const int r0_ = (ROW);                                                    \
    if (r0_ >= 0 && r0_ < H) {                                                \
      LOADROW_V(P + r0_ * W, A0);                                             \
      LOADROW_V(T + r0_ * W, B0);                                             \
    } else {                                                                  \
      _Pragma("unroll") for (int c_ = 0; c_ < 5; ++c_) {                      \
        A0[c_] = 0.f; B0[c_] = 0.f;                                           \
      }                                                                       \
    }                                                                         \
    if (r0_ + 1 >= 0 && r0_ + 1 < H) {                                        \
      LOADROW_V(P + (r0_ + 1) * W, A1);                                       \
      LOADROW_V(T + (r0_ + 1) * W, B1);                                       \
    } else {                                                                  \
      _Pragma("unroll") for (int c_ = 0; c_ < 5; ++c_) {                      \
        A1[c_] = 0.f; B1[c_] = 0.f;                                           \
      }                                                                       \
    }                                                                         \
  } while (0)

// Pack (p,t) row-pair -> (s',d') ring slot: s'=p+t, d'=p-t (the /2 folds
// into the epilogue constants).
#define PACKTO(J, A0, B0, A1, B1)                                             \
  do {                                                                        \
    _Pragma("unroll") for (int c_ = 0; c_ < 5; ++c_) {                        \
      const h2 hp_ = pkrtz(A0[c_], A1[c_]);                                   \
      const h2 ht_ = pkrtz(B0[c_], B1[c_]);                                   \
      rs[J][c_] = hp_ + ht_;                                                  \
      rd[J][c_] = hp_ - ht_;                                                  \
    }                                                                         \
  } while (0)

#define HALO(PKc, L, R)                                                       \
  do {                                                                        \
    _Pragma("unroll") for (int c_ = 0; c_ < 5; ++c_) {                        \
      L[c_] = dpp_up1(PKc[c_]);                                               \
      R[c_] = dpp_dn1(PKc[c_]);                                               \
    }                                                                         \
  } while (0)

// 9-tap horizontal blur: output col c reads cols c-4..c+4.
#define XCOL(PKc, L, R, G)                                                    \
  (((G) < 0) ? L[(G) + 5] : (((G) <= 4) ? PKc[(G)] : R[(G) - 5]))

// Symmetric pairing: O = w4*x[c] + sum_{k=0..3} w[k]*(x[c-4+k]+x[c+4-k]).
#define HBLUR9S(PKc, L, R, O)                                                 \
  do {                                                                        \
    _Pragma("unroll") for (int c_ = 0; c_ < 5; ++c_) {                        \
      h2 a_ = W9H[4] * PKc[c_];                                               \
      _Pragma("unroll") for (int k_ = 0; k_ < 4; ++k_) {                      \
        const h2 pr_ = XCOL(PKc, L, R, c_ - 4 + k_) +                         \
                       XCOL(PKc, L, R, c_ + 4 - k_);                          \
        a_ = W9H[k_] * pr_ + a_;                                              \
      }                                                                       \
      O[c_] = a_;                                                             \
    }                                                                         \
  } while (0)

// One output-row-pair at static window slots I..I+4, packed-f16 epilogue.
#define COMPUTE(I)                                                            \
  do {                                                                        \
    h2 PK[4][5];                                                              \
    _Pragma("unroll") for (int c = 0; c < 5; ++c) {                           \
      float sA = 0, dA = 0, ssA = 0, ddA = 0;                                 \
      float sB = 0, dB = 0, ssB = 0, ddB = 0;                                 \
      _Pragma("unroll") for (int j = 0; j < 5; ++j) {                         \
        const h2 a = rs[(I) + j][c], b = rd[(I) + j][c];                      \
        const h2 aa = a * a, bb = b * b;                                      \
        const h2 wa = wAv[j], wb = wBv[j];                                    \
        sA  = fdot2f(wa, a, sA);                                              \
        dA  = fdot2f(wa, b, dA);                                              \
        ssA = fdot2f(wa, aa, ssA);                                            \
        ddA = fdot2f(wa, bb, ddA);                                            \
        sB  = fdot2f(wb, a, sB);                                              \
        dB  = fdot2f(wb, b, dB);                                              \
        ssB = fdot2f(wb, aa, ssB);                                            \
        ddB = fdot2f(wb, bb, ddB);                                            \
      }                                                                       \
      PK[0][c] = pkrtz(sA, sB);                                               \
      PK[1][c] = pkrtz(dA, dB);                                               \
      PK[2][c] = pkrtz(ssA, ssB);                                             \
      PK[3][c] = pkrtz(ddA, ddB);                                             \
    }                                                                         \
    h2 OUT[4][5];                                                             \
    _Pragma("unroll") for (int ch = 0; ch < 4; ++ch) {                        \
      h2 L[5], R[5];                                                          \
      HALO(PK[ch], L, R);                                                     \
      HBLUR9S(PK[ch], L, R, OUT[ch]);                                         \
    }                                                                         \
    _Pragma("unroll") for (int c = 0; c < 5; ++c) {                           \
      const h2 U = OUT[0][c], V = OUT[1][c];                                  \
      const h2 w_ = OUT[2][c], x_ = OUT[3][c];                                \
      const h2 uu = U * U, vv = V * V;                                        \
      const h2 Ap = uu + vv, Bq = uu - vv;                                    \
      const h2 n1 = Bq * HALFp + C1p;                 /* 2mxy+C1   */         \
      const h2 n2 = ((w_ - x_) - Bq) * HALFp + C2p;   /* 2vxy+C2   */         \
      const h2 d1 = Ap * HALFp + C1p;                 /* mxx+myy+C1*/         \
      const h2 d2 = ((w_ + x_) - Ap) * HALFp + C2p;   /* vx+vy+C2  */         \
      const h2 NU = n1 * n2, DE = d1 * d2;                                    \
      acc = fmaf((float)NU.x, rcpf((float)DE.x), acc);                        \
      acc = fmaf((float)NU.y, rcpf((float)DE.y), acc);                        \
    }                                                                         \
  } while (0)

__global__ __launch_bounds__(64) void ssim_main(
    const float* __restrict__ pred, const float* __restrict__ targ,
    float* __restrict__ sink, int slotmask, int sstr) {
  const int lane = threadIdx.x & 63;
  const int stripe = blockIdx.x;
  const int img = stripe / NSTRIPE;
  const int y0  = (stripe % NSTRIPE) * TH;

  const float* __restrict__ P = pred + (size_t)img * (W * H) + 5 * lane;
  const float* __restrict__ T = targ + (size_t)img * (W * H) + 5 * lane;

  // 9-tap truncated + renormalized Gaussian (sigma=1.5).
  constexpr float W9[9] = {0.00761451f, 0.03607501f, 0.10958607f, 0.21344455f,
                           0.26655996f, 0.21344455f, 0.10958607f, 0.03607501f,
                           0.00761451f};
  const h2 wAv[5] = {pack2(W9[0], W9[1]), pack2(W9[2], W9[3]),
                     pack2(W9[4], W9[5]), pack2(W9[6], W9[7]),
                     pack2(W9[8], 0.f)};
  const h2 wBv[5] = {pack2(0.f, W9[0]),   pack2(W9[1], W9[2]),
                     pack2(W9[3], W9[4]), pack2(W9[5], W9[6]),
                     pack2(W9[7], W9[8])};
  h2 W9H[5];
#pragma unroll
  for (int k = 0; k < 5; ++k) W9H[k] = pack2(W9[k], W9[k]);
  const h2 HALFp = pack2(0.5f, 0.5f);
  const h2 C1p = pack2(C1, C1);
  const h2 C2p = pack2(C2, C2);

  // Ring: 6 row-pairs, (s',d') packed (rowA,rowB) per col.
  h2 rs[6][5], rd[6][5];

  // ---- staggered preamble: pairs 0..5 (rows y0-4 .. y0+7) -> slots 0..5 ----
  {
    float aA[5], bA[5], cA[5], dA[5];
    float aB[5], bB[5], cB[5], dB[5];
    LOADP_RAW(y0 - 4, aA, bA, cA, dA);
    LOADP_RAW(y0 - 2, aB, bB, cB, dB);
    PACKTO(0, aA, bA, cA, dA);
    LOADP_RAW(y0 + 0, aA, bA, cA, dA);
    PACKTO(1, aB, bB, cB, dB);
    LOADP_RAW(y0 + 2, aB, bB, cB, dB);
    PACKTO(2, aA, bA, cA, dA);
    LOADP_RAW(y0 + 4, aA, bA, cA, dA);
    PACKTO(3, aB, bB, cB, dB);
    LOADP_RAW(y0 + 6, aB, bB, cB, dB);
    PACKTO(4, aA, bA, cA, dA);
    PACKTO(5, aB, bB, cB, dB);
  }

  float acc = 0.f;
  float nfA[5], ntA[5], nfB[5], ntB[5];
  float mfA[5], mtA[5], mfB[5], mtB[5];

  // 4 blocks: block b outputs rows y0+4b .. y0+4b+3 from window slots 0-4/1-5
  // (pairs 2b..2b+5 after b slides); prefetch pairs 2b+6, 2b+7 while computing.
#pragma unroll 1
  for (int b = 0; b < 4; ++b) {
    const int yb = y0 + 4 * b;
    if (b < 3) LOADP_RAW(yb + 8, nfA, ntA, nfB, ntB);
    COMPUTE(0);
    if (b < 3) LOADP_RAW(yb + 10, mfA, mtA, mfB, mtB);
    COMPUTE(1);
    if (b < 3) {
#pragma unroll
      for (int j = 0; j < 4; ++j)
#pragma unroll
        for (int c = 0; c < 5; ++c) {
          rs[j][c] = rs[j + 2][c];
          rd[j][c] = rd[j + 2][c];
        }
      PACKTO(4, nfA, ntA, nfB, ntB);
      PACKTO(5, mfA, mtA, mfB, mtB);
    }
  }

  // ---- wave reduce + spread atomics ----
#pragma unroll
  for (int off = 32; off; off >>= 1) acc += __shfl_xor(acc, off, 64);
  if (lane == 0) atomicAdd(sink + (stripe & slotmask) * sstr, acc);
}

__global__ void ssim_final(const float* __restrict__ sink, int nslot, int sstr,
                           float* __restrict__ out) {
  const int tid = threadIdx.x;  // 64 threads
  float v = 0.f;
  for (int s = tid; s < nslot; s += 64) v += sink[s * sstr];
#pragma unroll
  for (int off = 32; off; off >>= 1) v += __shfl_xor(v, off, 64);
  if (tid == 0) out[0] = 1.f - v / 13107200.f;
}

extern "C" void kernel_launch(void* const* d_in, const int* in_sizes, int n_in,
                              void* d_out, int out_size, void* d_ws, size_t ws_size,
                              hipStream_t stream) {
  (void)in_sizes; (void)n_in; (void)out_size;
  const float* pred = (const float*)d_in[0];
  const float* targ = (const float*)d_in[1];
  float* out = (float*)d_out;

  float* sink;
  int nslot, sstr;
  const size_t need = (size_t)NSLOT * SSTR * sizeof(float);
  if (ws_size >= need) {
    sink = (float*)d_ws;
    nslot = NSLOT;
    sstr = SSTR;
  } else {
    sink = out;
    nslot = 1;
    sstr = 0;
  }
  (void)hipMemsetAsync(sink, 0, nslot == 1 ? sizeof(float) : need, stream);
  ssim_main<<<dim3(NWAVE), dim3(64), 0, stream>>>(pred, targ, sink, nslot - 1, sstr);
  ssim_final<<<1, 64, 0, stream>>>(sink, nslot, sstr, out);
}

// Round 20
// 48.927 us; speedup vs baseline: 1.0491x; 1.0491x over previous
//
#include <hip/hip_runtime.h>

// SSIM loss v19: v17 exactly (TH=8, packed-f16 epilogue, unscaled s'/d',
// block-of-2 static windows, DPP halo) + symmetric-pair 9-tap hblur
// (w[k]=w[8-k]: mirror taps pre-added, 9 ops vs 10 per col-channel).
// Isolates v18's micro-opt from its TH=16 TLP regression.

namespace {
constexpr int W = 320, H = 320, B = 128;
constexpr int TH = 8;
constexpr int NSTRIPE = H / TH;     // 40
constexpr int NWAVE = B * NSTRIPE;  // 5120 (= 5 waves/SIMD, the TLP sweet spot)
constexpr float C1 = 1.0e-4f;
constexpr float C2 = 9.0e-4f;
constexpr int NSLOT = 128;
constexpr int SSTR = 16;
}

typedef _Float16 h2 __attribute__((ext_vector_type(2)));
typedef float f4a __attribute__((ext_vector_type(4), aligned(4)));

__device__ __forceinline__ float fdot2f(h2 a, h2 b, float c) {
#if __has_builtin(__builtin_amdgcn_fdot2)
  return __builtin_amdgcn_fdot2(a, b, c, false);
#else
  return fmaf((float)a.x, (float)b.x, fmaf((float)a.y, (float)b.y, c));
#endif
}

__device__ __forceinline__ float rcpf(float x) {
  float r;
  asm("v_rcp_f32 %0, %1" : "=v"(r) : "v"(x));
  return r;
}

__device__ __forceinline__ h2 pack2(float a, float b) {
  return h2{(_Float16)a, (_Float16)b};
}

__device__ __forceinline__ h2 pkrtz(float a, float b) {
#if __has_builtin(__builtin_amdgcn_cvt_pkrtz)
  return __builtin_bit_cast(h2, __builtin_amdgcn_cvt_pkrtz(a, b));
#else
  return pack2(a, b);
#endif
}

// lane i <- lane i-1, lane 0 <- 0 (wave_shr:1, bound_ctrl). [HW-verified]
__device__ __forceinline__ h2 dpp_up1(h2 v) {
  int r = __builtin_amdgcn_update_dpp(0, __builtin_bit_cast(int, v),
                                      0x138, 0xF, 0xF, true);
  return __builtin_bit_cast(h2, r);
}
// lane i <- lane i+1, lane 63 <- 0 (wave_shl:1, bound_ctrl). [HW-verified]
__device__ __forceinline__ h2 dpp_dn1(h2 v) {
  int r = __builtin_amdgcn_update_dpp(0, __builtin_bit_cast(int, v),
                                      0x130, 0xF, 0xF, true);
  return __builtin_bit_cast(h2, r);
}

#define LOADROW_V(PTR, A)                                                     \
  do {                                                                        \
    const f4a q_ = *(const f4a*)(PTR);                                        \
    A[0] = q_.x; A[1] = q_.y; A[2] = q_.z; A[3] = q_.w;                       \
    A[4] = (PTR)[4];                                                          \
  } while (0)

#define LOADP_RAW(ROW, A0, B0, A1, B1)                                        \
  do {                                                                        \
    const int r0_ = (ROW);                                                    \
    if (r0_ >= 0 && r0_ < H) {                                                \
      LOADROW_V(P + r0_ * W, A0);                                             \
      LOADROW_V(T + r0_ * W, B0);                                             \
    } else {                                                                  \
      _Pragma("unroll") for (int c_ = 0; c_ < 5; ++c_) {                      \
        A0[c_] = 0.f; B0[c_] = 0.f;                                           \
      }                                                                       \
    }                                                                         \
    if (r0_ + 1 >= 0 && r0_ + 1 < H) {                                        \
      LOADROW_V(P + (r0_ + 1) * W, A1);                                       \
      LOADROW_V(T + (r0_ + 1) * W, B1);                                       \
    } else {                                                                  \
      _Pragma("unroll") for (int c_ = 0; c_ < 5; ++c_) {                      \
        A1[c_] = 0.f; B1[c_] = 0.f;                                           \
      }                                                                       \
    }                                                                         \
  } while (0)

// Pack (p,t) row-pair -> (s',d') ring slot: s'=p+t, d'=p-t.
#define PACKTO(J, A0, B0, A1, B1)                                             \
  do {                                                                        \
    _Pragma("unroll") for (int c_ = 0; c_ < 5; ++c_) {                        \
      const h2 hp_ = pkrtz(A0[c_], A1[c_]);                                   \
      const h2 ht_ = pkrtz(B0[c_], B1[c_]);                                   \
      rs[J][c_] = hp_ + ht_;                                                  \
      rd[J][c_] = hp_ - ht_;                                                  \
    }                                                                         \
  } while (0)

#define HALO(PKc, L, R)                                                       \
  do {                                                                        \
    _Pragma("unroll") for (int c_ = 0; c_ < 5; ++c_) {                        \
      L[c_] = dpp_up1(PKc[c_]);                                               \
      R[c_] = dpp_dn1(PKc[c_]);                                               \
    }                                                                         \
  } while (0)

// 9-tap horizontal blur: output col c reads cols c-4..c+4.
#define XCOL(PKc, L, R, G)                                                    \
  (((G) < 0) ? L[(G) + 5] : (((G) <= 4) ? PKc[(G)] : R[(G) - 5]))

// Symmetric pairing: O = w4*x[c] + sum_{k=0..3} w[k]*(x[c-4+k]+x[c+4-k]).
#define HBLUR9S(PKc, L, R, O)                                                 \
  do {                                                                        \
    _Pragma("unroll") for (int c_ = 0; c_ < 5; ++c_) {                        \
      h2 a_ = W9H[4] * PKc[c_];                                               \
      _Pragma("unroll") for (int k_ = 0; k_ < 4; ++k_) {                      \
        const h2 pr_ = XCOL(PKc, L, R, c_ - 4 + k_) +                         \
                       XCOL(PKc, L, R, c_ + 4 - k_);                          \
        a_ = W9H[k_] * pr_ + a_;                                              \
      }                                                                       \
      O[c_] = a_;                                                             \
    }                                                                         \
  } while (0)

// One output-row-pair at static window slots I..I+4, packed-f16 epilogue.
#define COMPUTE(I)                                                            \
  do {                                                                        \
    h2 PK[4][5];                                                              \
    _Pragma("unroll") for (int c = 0; c < 5; ++c) {                           \
      float sA = 0, dA = 0, ssA = 0, ddA = 0;                                 \
      float sB = 0, dB = 0, ssB = 0, ddB = 0;                                 \
      _Pragma("unroll") for (int j = 0; j < 5; ++j) {                         \
        const h2 a = rs[(I) + j][c], b = rd[(I) + j][c];                      \
        const h2 aa = a * a, bb = b * b;                                      \
        const h2 wa = wAv[j], wb = wBv[j];                                    \
        sA  = fdot2f(wa, a, sA);                                              \
        dA  = fdot2f(wa, b, dA);                                              \
        ssA = fdot2f(wa, aa, ssA);                                            \
        ddA = fdot2f(wa, bb, ddA);                                            \
        sB  = fdot2f(wb, a, sB);                                              \
        dB  = fdot2f(wb, b, dB);                                              \
        ssB = fdot2f(wb, aa, ssB);                                            \
        ddB = fdot2f(wb, bb, ddB);                                            \
      }                                                                       \
      PK[0][c] = pkrtz(sA, sB);                                               \
      PK[1][c] = pkrtz(dA, dB);                                               \
      PK[2][c] = pkrtz(ssA, ssB);                                             \
      PK[3][c] = pkrtz(ddA, ddB);                                             \
    }                                                                         \
    h2 OUT[4][5];                                                             \
    _Pragma("unroll") for (int ch = 0; ch < 4; ++ch) {                        \
      h2 L[5], R[5];                                                          \
      HALO(PK[ch], L, R);                                                     \
      HBLUR9S(PK[ch], L, R, OUT[ch]);                                         \
    }                                                                         \
    _Pragma("unroll") for (int c = 0; c < 5; ++c) {                           \
      const h2 U = OUT[0][c], V = OUT[1][c];                                  \
      const h2 w_ = OUT[2][c], x_ = OUT[3][c];                                \
      const h2 uu = U * U, vv = V * V;                                        \
      const h2 Ap = uu + vv, Bq = uu - vv;                                    \
      const h2 n1 = Bq * HALFp + C1p;                 /* 2mxy+C1   */         \
      const h2 n2 = ((w_ - x_) - Bq) * HALFp + C2p;   /* 2vxy+C2   */         \
      const h2 d1 = Ap * HALFp + C1p;                 /* mxx+myy+C1*/         \
      const h2 d2 = ((w_ + x_) - Ap) * HALFp + C2p;   /* vx+vy+C2  */         \
      const h2 NU = n1 * n2, DE = d1 * d2;                                    \
      acc = fmaf((float)NU.x, rcpf((float)DE.x), acc);                        \
      acc = fmaf((float)NU.y, rcpf((float)DE.y), acc);                        \
    }                                                                         \
  } while (0)

__global__ __launch_bounds__(64) void ssim_main(
    const float* __restrict__ pred, const float* __restrict__ targ,
    float* __restrict__ sink, int slotmask, int sstr) {
  const int lane = threadIdx.x & 63;
  const int stripe = blockIdx.x;
  const int img = stripe / NSTRIPE;
  const int y0  = (stripe % NSTRIPE) * TH;

  const float* __restrict__ P = pred + (size_t)img * (W * H) + 5 * lane;
  const float* __restrict__ T = targ + (size_t)img * (W * H) + 5 * lane;

  // 9-tap truncated + renormalized Gaussian (sigma=1.5).
  constexpr float W9[9] = {0.00761451f, 0.03607501f, 0.10958607f, 0.21344455f,
                           0.26655996f, 0.21344455f, 0.10958607f, 0.03607501f,
                           0.00761451f};
  const h2 wAv[5] = {pack2(W9[0], W9[1]), pack2(W9[2], W9[3]),
                     pack2(W9[4], W9[5]), pack2(W9[6], W9[7]),
                     pack2(W9[8], 0.f)};
  const h2 wBv[5] = {pack2(0.f, W9[0]),   pack2(W9[1], W9[2]),
                     pack2(W9[3], W9[4]), pack2(W9[5], W9[6]),
                     pack2(W9[7], W9[8])};
  h2 W9H[5];
#pragma unroll
  for (int k = 0; k < 5; ++k) W9H[k] = pack2(W9[k], W9[k]);
  const h2 HALFp = pack2(0.5f, 0.5f);
  const h2 C1p = pack2(C1, C1);
  const h2 C2p = pack2(C2, C2);

  // Ring: 6 row-pairs, (s',d') packed (rowA,rowB) per col.
  h2 rs[6][5], rd[6][5];

  // ---- staggered preamble: pairs 0..5 (rows y0-4 .. y0+7) -> slots 0..5 ----
  {
    float aA[5], bA[5], cA[5], dA[5];
    float aB[5], bB[5], cB[5], dB[5];
    LOADP_RAW(y0 - 4, aA, bA, cA, dA);
    LOADP_RAW(y0 - 2, aB, bB, cB, dB);
    PACKTO(0, aA, bA, cA, dA);
    LOADP_RAW(y0 + 0, aA, bA, cA, dA);
    PACKTO(1, aB, bB, cB, dB);
    LOADP_RAW(y0 + 2, aB, bB, cB, dB);
    PACKTO(2, aA, bA, cA, dA);
    LOADP_RAW(y0 + 4, aA, bA, cA, dA);
    PACKTO(3, aB, bB, cB, dB);
    LOADP_RAW(y0 + 6, aB, bB, cB, dB);
    PACKTO(4, aA, bA, cA, dA);
    PACKTO(5, aB, bB, cB, dB);
  }

  float acc = 0.f;
  float nfA[5], ntA[5], nfB[5], ntB[5];   // pair 6 prefetch
  float mfA[5], mtA[5], mfB[5], mtB[5];   // pair 7 prefetch

  // Block b=0: outputs (y0..y0+3) from pairs 0-5; prefetch pairs 6,7; slide.
  // Block b=1: outputs (y0+4..y0+7) from pairs 2-7 (now in slots 0-5).
#pragma unroll 1
  for (int b = 0; b < 2; ++b) {
    if (b == 0) LOADP_RAW(y0 + 8, nfA, ntA, nfB, ntB);    // pair 6
    COMPUTE(0);                                           // window slots 0..4
    if (b == 0) LOADP_RAW(y0 + 10, mfA, mtA, mfB, mtB);   // pair 7
    COMPUTE(1);                                           // window slots 1..5
    if (b == 0) {
#pragma unroll
      for (int j = 0; j < 4; ++j)
#pragma unroll
        for (int c = 0; c < 5; ++c) {
          rs[j][c] = rs[j + 2][c];
          rd[j][c] = rd[j + 2][c];
        }
      PACKTO(4, nfA, ntA, nfB, ntB);
      PACKTO(5, mfA, mtA, mfB, mtB);
    }
  }

  // ---- wave reduce + spread atomics ----
#pragma unroll
  for (int off = 32; off; off >>= 1) acc += __shfl_xor(acc, off, 64);
  if (lane == 0) atomicAdd(sink + (stripe & slotmask) * sstr, acc);
}

__global__ void ssim_final(const float* __restrict__ sink, int nslot, int sstr,
                           float* __restrict__ out) {
  const int tid = threadIdx.x;  // 64 threads
  float v = 0.f;
  for (int s = tid; s < nslot; s += 64) v += sink[s * sstr];
#pragma unroll
  for (int off = 32; off; off >>= 1) v += __shfl_xor(v, off, 64);
  if (tid == 0) out[0] = 1.f - v / 13107200.f;
}

extern "C" void kernel_launch(void* const* d_in, const int* in_sizes, int n_in,
                              void* d_out, int out_size, void* d_ws, size_t ws_size,
                              hipStream_t stream) {
  (void)in_sizes; (void)n_in; (void)out_size;
  const float* pred = (const float*)d_in[0];
  const float* targ = (const float*)d_in[1];
  float* out = (float*)d_out;

  float* sink;
  int nslot, sstr;
  const size_t need = (size_t)NSLOT * SSTR * sizeof(float);
  if (ws_size >= need) {
    sink = (float*)d_ws;
    nslot = NSLOT;
    sstr = SSTR;
  } else {
    sink = out;
    nslot = 1;
    sstr = 0;
  }
  (void)hipMemsetAsync(sink, 0, nslot == 1 ? sizeof(float) : need, stream);
  ssim_main<<<dim3(NWAVE), dim3(64), 0, stream>>>(pred, targ, sink, nslot - 1, sstr);
  ssim_final<<<1, 64, 0, stream>>>(sink, nslot, sstr, out);
}